// Round 1
// 189.014 us; speedup vs baseline: 1.1168x; 1.1168x over previous
//
#include <hip/hip_runtime.h>

#define H 256
#define W 256
#define BATCH 8
#define CIN 16
#define TW 64
#define TH 4
#define HWC (TW + 2)        // 66 halo cols
#define HHC (TH + 2)        // 6 halo rows
#define NHALO (HWC * HHC)   // 396 halo pixels
#define PSTR 24             // shorts per halo pixel (16 data + 8 pad): 48B stride -> bank-balanced
#define FIX_CAP 16384
#define GAP_TAU 1e-3f

// LDS layout (bytes): [hHi 19008][hS 19008][gsL 1584][bufB 2*16384] = 72368
// epilogue overlays float scratch from offset 0 (4 waves * 4352 floats = 69632 B)
#define OFF_HS   19008
#define OFF_GS   38016
#define OFF_BB   39600
#define SMEM_BYTES 72368

typedef __attribute__((ext_vector_type(8))) short short8;       // 8 fp16 bit-patterns
typedef __attribute__((ext_vector_type(8))) _Float16 half8;     // MFMA A/B frag
typedef __attribute__((ext_vector_type(4))) float f32x4;        // MFMA C/D frag

union S8H8 { short8 s; half8 h; };
__device__ __forceinline__ half8 as_h8(short8 s) { S8H8 u; u.s = s; return u.h; }
union HU { _Float16 h; unsigned short u; };

__device__ __forceinline__ void gload_lds16(const void* g, void* l) {
    __builtin_amdgcn_global_load_lds(
        (const __attribute__((address_space(1))) unsigned int*)g,
        (__attribute__((address_space(3))) unsigned int*)l, 16, 0, 0);
}

__device__ __forceinline__ float4 add4(float4 a, float4 b) {
    return make_float4(a.x + b.x, a.y + b.y, a.z + b.z, a.w + b.w);
}
__device__ __forceinline__ float max4(float4 a) {
    return fmaxf(fmaxf(a.x, a.y), fmaxf(a.z, a.w));
}

// weight [oc][ic][3][3] fp32 -> wt[tap][sel][n=oc][k=ic swizzled] fp16 bits; w pre-scaled x64
// sel=0: bh = fp16(w*64); sel=1: T = bh (+) fp16((w*64-bh)*2048)   (S.T-combine trick)
// k column XOR-swizzled by (n&7)<<3 so that a LINEAR global->LDS copy yields
// conflict-free ds_read_b128 at read time (read applies the same XOR).
__global__ void wprep_kernel(const float* __restrict__ w, unsigned short* __restrict__ wt) {
    int i = blockIdx.x * 256 + threadIdx.x;   // 9*2*64*64 = 73728
    if (i >= 73728) return;
    int k   = i & 63;
    int n   = (i >> 6) & 63;
    int sel = (i >> 12) & 1;
    int tap = i >> 13;
    float v = w[(n * 64 + k) * 9 + tap] * 64.0f;
    HU uh; uh.h = (_Float16)v;
    unsigned short ob;
    if (sel == 0) {
        ob = uh.u;
    } else {
        _Float16 lo = (_Float16)((v - (float)uh.h) * 2048.0f);
        HU us; us.h = (_Float16)(uh.h + lo);
        ob = us.u;
    }
    int ksw = k ^ ((n & 7) << 3);
    wt[(((tap * 2 + sel) * 64) + n) * 64 + ksw] = ob;
}

// per-element: store hi = fp16(f) and S = hi (+) fp16((f-hi)*2048)
#define CVT(F, VH, VS, J) { HU uh_; uh_.h = (_Float16)(F); \
    _Float16 lo_ = (_Float16)(((F) - (float)uh_.h) * 2048.0f); \
    HU us_; us_.h = (_Float16)(uh_.h + lo_); \
    VH[J] = (short)uh_.u; VS[J] = (short)us_.u; }

__global__ __launch_bounds__(256, 2) void ssconv_mfma_kernel(
    const float* __restrict__ x, const int* __restrict__ gidx,
    const unsigned short* __restrict__ wt, const float* __restrict__ bias,
    float* __restrict__ out_sel, float* __restrict__ out_idx,
    unsigned* __restrict__ fix_cnt, unsigned* __restrict__ fix_list)
{
    __shared__ __align__(16) char smem[SMEM_BYTES];
    unsigned short* hHi  = (unsigned short*)smem;
    unsigned short* hS   = (unsigned short*)(smem + OFF_HS);
    int* gsL             = (int*)(smem + OFF_GS);
    unsigned short* bufB = (unsigned short*)(smem + OFF_BB);
    float* outS          = (float*)smem;          // epilogue overlay

    const int tid  = threadIdx.x;
    const int x0   = blockIdx.x * TW;
    const int y0   = blockIdx.y * TH;
    const int bz   = blockIdx.z;
    const int wvid = tid >> 6;        // wave id 0..3 -> tile row
    const int L    = tid & 63;
    const int q    = L >> 4;          // quad
    const int lm   = L & 15;
    const int c0   = (q & 1) * 8;     // channel half within pixel

    // ---- issue B(tap=0) -> bufB[0] (async, drained by the barrier below) ----
#pragma unroll
    for (int c = 0; c < 4; ++c) {
        int seg = wvid * 4 + c;                       // 16 segments of 1KB
        gload_lds16((const char*)wt + seg * 1024 + L * 16,
                    (char*)bufB + seg * 1024);
    }

    // ---- stage halo as fp16 hi / S + group map ----
    for (int i = tid; i < NHALO; i += 256) {
        int r = i / HWC, c = i % HWC;
        int hy = y0 + r - 1, hx = x0 + c - 1;
        bool ok = (hy >= 0) && (hy < H) && (hx >= 0) && (hx < W);
        float4 a0 = make_float4(0, 0, 0, 0), a1 = a0, a2 = a0, a3 = a0;
        int g = 0;
        if (ok) {
            const float4* src = (const float4*)(x + (((size_t)bz * H + hy) * W + hx) * CIN);
            a0 = src[0]; a1 = src[1]; a2 = src[2]; a3 = src[3];
            g = gidx[((size_t)bz * H + hy) * W + hx];
        }
        gsL[i] = g;
        short8 vh0, vs0, vh1, vs1;
        CVT(a0.x, vh0, vs0, 0) CVT(a0.y, vh0, vs0, 1) CVT(a0.z, vh0, vs0, 2) CVT(a0.w, vh0, vs0, 3)
        CVT(a1.x, vh0, vs0, 4) CVT(a1.y, vh0, vs0, 5) CVT(a1.z, vh0, vs0, 6) CVT(a1.w, vh0, vs0, 7)
        CVT(a2.x, vh1, vs1, 0) CVT(a2.y, vh1, vs1, 1) CVT(a2.z, vh1, vs1, 2) CVT(a2.w, vh1, vs1, 3)
        CVT(a3.x, vh1, vs1, 4) CVT(a3.y, vh1, vs1, 5) CVT(a3.z, vh1, vs1, 6) CVT(a3.w, vh1, vs1, 7)
        *(short8*)&hHi[i * PSTR + 0] = vh0;
        *(short8*)&hHi[i * PSTR + 8] = vh1;
        *(short8*)&hS[i * PSTR + 0]  = vs0;
        *(short8*)&hS[i * PSTR + 8]  = vs1;
    }
    __syncthreads();

    f32x4 acch[4][4] = {};   // ah*bh   (units: 64x true)
    f32x4 accc[4][4] = {};   // S*T     (= ah*bh + cross/1 + negligible)

#pragma unroll 1
    for (int tap = 0; tap < 9; ++tap) {
        // prefetch next tap's B into the other buffer (in flight across this tap's MFMAs)
        if (tap < 8) {
            const char* gsrc = (const char*)(wt + (size_t)(tap + 1) * 8192);
            char* ldst = (char*)bufB + ((tap + 1) & 1) * 16384;
#pragma unroll
            for (int c = 0; c < 4; ++c) {
                int seg = wvid * 4 + c;
                gload_lds16(gsrc + seg * 1024 + L * 16, ldst + seg * 1024);
            }
        }
        const unsigned short* bb = bufB + (tap & 1) * 8192;

        const int dy = tap / 3, dx = tap % 3;
        const int hbase = (wvid + dy) * HWC + lm + dx;

        // A fragments: loaded ONCE per tap (shared across both ks chunks)
        short8 ah[4], aS[4];
        int gg[4];
#pragma unroll
        for (int m = 0; m < 4; ++m) {
            int hb = hbase + 16 * m;
            gg[m] = gsL[hb];
            ah[m] = *(const short8*)&hHi[hb * PSTR + c0];
            aS[m] = *(const short8*)&hS[hb * PSTR + c0];
        }

#pragma unroll
        for (int ks = 0; ks < 2; ++ks) {
            const int gk = ks * 2 + (q >> 1);
            const int kcol = (ks * 32 + q * 8) ^ ((lm & 7) << 3);   // matches wprep swizzle
            short8 bh[4], bt[4];
#pragma unroll
            for (int nt = 0; nt < 4; ++nt) {
                bh[nt] = *(const short8*)&bb[(nt * 16 + lm) * 64 + kcol];
                bt[nt] = *(const short8*)&bb[(64 + nt * 16 + lm) * 64 + kcol];
            }
            const short8 z = (short8)0;
#pragma unroll
            for (int m = 0; m < 4; ++m) {
                bool mm = (gg[m] == gk);
                short8 a0 = mm ? ah[m] : z;
                short8 s0 = mm ? aS[m] : z;
#pragma unroll
                for (int nt = 0; nt < 4; ++nt) {
                    acch[m][nt] = __builtin_amdgcn_mfma_f32_16x16x32_f16(as_h8(a0), as_h8(bh[nt]), acch[m][nt], 0, 0, 0);
                    accc[m][nt] = __builtin_amdgcn_mfma_f32_16x16x32_f16(as_h8(s0), as_h8(bt[nt]), accc[m][nt], 0, 0, 0);
                }
            }
        }
        __syncthreads();   // one barrier per tap: drains prefetch vmcnt + guards buffer swap
    }

    // ---- epilogue: out = acc_h*(1/64 - 2^-17) + acc_c*2^-17  -> LDS overlay ----
    const float SHm = 2047.0f / 131072.0f;   // exact in fp32
    const float SLc = 1.0f / 131072.0f;      // 2^-17
#pragma unroll
    for (int m = 0; m < 4; ++m)
#pragma unroll
        for (int nt = 0; nt < 4; ++nt)
#pragma unroll
            for (int r = 0; r < 4; ++r) {
                int xcol = 16 * m + q * 4 + r;            // pixel within row, 0..63
                outS[wvid * 4352 + xcol * 68 + nt * 16 + lm] =
                    acch[m][nt][r] * SHm + accc[m][nt][r] * SLc;
            }
    __syncthreads();

    // ---- per-pixel maxout/argmax/select: 2 threads per pixel, 2 passes over 256 px ----
#pragma unroll 1
    for (int pp = 0; pp < 2; ++pp) {
        int p  = (tid >> 1) + pp * 128;   // tile pixel 0..255
        int hh = tid & 1;                 // channel half
        int pw = p >> 6, px_ = p & 63;
        const float4* srcp = (const float4*)(outS + pw * 4352 + px_ * 68 + hh * 32);
        const float4* bb2 = (const float4*)(bias + hh * 32);
        float4 r0 = add4(srcp[0], bb2[0]), r1 = add4(srcp[1], bb2[1]);
        float4 r2 = add4(srcp[2], bb2[2]), r3 = add4(srcp[3], bb2[3]);
        float4 r4 = add4(srcp[4], bb2[4]), r5 = add4(srcp[5], bb2[5]);
        float4 r6 = add4(srcp[6], bb2[6]), r7 = add4(srcp[7], bb2[7]);

        float ma = fmaxf(fmaxf(max4(r0), max4(r1)), fmaxf(max4(r2), max4(r3)));
        float mb = fmaxf(fmaxf(max4(r4), max4(r5)), fmaxf(max4(r6), max4(r7)));
        float pa = __shfl_xor(ma, 1, 64);
        float pb = __shfl_xor(mb, 1, 64);
        float s0, s1, s2, s3;
        if (hh == 0) { s0 = ma; s1 = mb; s2 = pa; s3 = pb; }
        else         { s0 = pa; s1 = pb; s2 = ma; s3 = mb; }
        int bg = 0; float best = s0;
        if (s1 > best) { best = s1; bg = 1; }
        if (s2 > best) { best = s2; bg = 2; }
        if (s3 > best) { best = s3; bg = 3; }

        int gy = y0 + pw, gx = x0 + px_;
        size_t opix = ((size_t)bz * H + gy) * W + gx;
        if ((bg >> 1) == hh) {
            bool useB = (bg & 1) != 0;
            float4 o0 = useB ? r4 : r0, o1 = useB ? r5 : r1;
            float4 o2 = useB ? r6 : r2, o3 = useB ? r7 : r3;
            float4* os = (float4*)(out_sel + opix * 16);
            os[0] = o0; os[1] = o1; os[2] = o2; os[3] = o3;
        }
        if (hh == 0) {
            out_idx[opix] = (float)bg;
            // flag near-ties for fp64 fix-up
            float o1v = (bg == 0) ? s1 : s0;
            float o2v = (bg <= 1) ? s2 : s1;
            float o3v = (bg <= 2) ? s3 : s2;
            float second = fmaxf(o1v, fmaxf(o2v, o3v));
            if (best - second < GAP_TAU) {
                unsigned slot = atomicAdd(fix_cnt, 1u);
                if (slot < FIX_CAP) fix_list[slot] = (unsigned)opix;
            }
        }
    }
}

// fp64 exact recompute of flagged pixels; one wave per pixel, lane = oc
__global__ void fixup_kernel(const float* __restrict__ x, const int* __restrict__ gidx,
                             const float* __restrict__ w, const float* __restrict__ bias,
                             float* __restrict__ out_sel, float* __restrict__ out_idx,
                             const unsigned* __restrict__ fix_cnt,
                             const unsigned* __restrict__ fix_list)
{
    unsigned n = *fix_cnt;
    if (n > FIX_CAP) n = FIX_CAP;
    const int lane = threadIdx.x & 63;
    const int nwaves = gridDim.x * (blockDim.x >> 6);
    unsigned widx = blockIdx.x * (blockDim.x >> 6) + (threadIdx.x >> 6);

    for (; widx < n; widx += nwaves) {
        unsigned opix = fix_list[widx];
        int b  = opix >> 16;
        int y  = (opix >> 8) & 255;
        int xc = opix & 255;
        double acc = (double)bias[lane];
        for (int dy = 0; dy < 3; ++dy) {
            int yy = y + dy - 1;
            if (yy < 0 || yy >= H) continue;
            for (int dx = 0; dx < 3; ++dx) {
                int xx = xc + dx - 1;
                if (xx < 0 || xx >= W) continue;
                size_t pix = ((size_t)b * H + yy) * W + xx;
                int g = gidx[pix];
                const float* xp = x + pix * 16;
                const float* wp = w + (size_t)(lane * 64 + g * 16) * 9 + (dy * 3 + dx);
#pragma unroll
                for (int c = 0; c < 16; ++c)
                    acc = fma((double)wp[c * 9], (double)xp[c], acc);
            }
        }
        // group max within 16-lane clusters
        double m = acc;
        m = fmax(m, __shfl_xor(m, 1, 64));
        m = fmax(m, __shfl_xor(m, 2, 64));
        m = fmax(m, __shfl_xor(m, 4, 64));
        m = fmax(m, __shfl_xor(m, 8, 64));
        double g0 = __shfl(m, 0, 64), g1 = __shfl(m, 16, 64);
        double g2 = __shfl(m, 32, 64), g3 = __shfl(m, 48, 64);
        int bg = 0; double bb = g0;
        if (g1 > bb) { bb = g1; bg = 1; }
        if (g2 > bb) { bb = g2; bg = 2; }
        if (g3 > bb) { bb = g3; bg = 3; }
        if ((lane >> 4) == bg) out_sel[(size_t)opix * 16 + (lane & 15)] = (float)acc;
        if (lane == 0) out_idx[opix] = (float)bg;
    }
}

extern "C" void kernel_launch(void* const* d_in, const int* in_sizes, int n_in,
                              void* d_out, int out_size, void* d_ws, size_t ws_size,
                              hipStream_t stream) {
    const float* x    = (const float*)d_in[0];
    const int*   gidx = (const int*)d_in[1];
    const float* w    = (const float*)d_in[2];
    const float* bias = (const float*)d_in[3];

    unsigned short* wt = (unsigned short*)d_ws;                    // 147456 B
    unsigned* fix_cnt  = (unsigned*)((char*)d_ws + 147456);        // 16 B
    unsigned* fix_list = (unsigned*)((char*)d_ws + 147472);        // 64 KB

    float* out_sel = (float*)d_out;                               // 8*256*256*16
    float* out_idx = (float*)d_out + (size_t)BATCH * H * W * CIN; // 8*256*256

    hipMemsetAsync(fix_cnt, 0, 16, stream);
    wprep_kernel<<<288, 256, 0, stream>>>(w, wt);

    dim3 grid(W / TW, H / TH, BATCH);   // 4 x 64 x 8 = 2048 blocks
    ssconv_mfma_kernel<<<grid, 256, 0, stream>>>(x, gidx, wt, bias, out_sel, out_idx,
                                                 fix_cnt, fix_list);
    fixup_kernel<<<256, 256, 0, stream>>>(x, gidx, w, bias, out_sel, out_idx,
                                          fix_cnt, fix_list);
}